// Round 6
// baseline (277.710 us; speedup 1.0000x reference)
//
#include <hip/hip_runtime.h>

#define NTOK 16384
#define BATCH 4

typedef __attribute__((ext_vector_type(8))) short bf16x8;
typedef __attribute__((ext_vector_type(8))) unsigned short ushort8;
typedef __attribute__((ext_vector_type(4))) float f32x4;

__device__ __forceinline__ unsigned short f2bf(float f) {
  union { float f; unsigned int u; } c; c.f = f;
  unsigned int r = c.u + 0x7fff + ((c.u >> 16) & 1);  // RTN-even
  return (unsigned short)(r >> 16);
}

__device__ __forceinline__ float exp2_fast(float x) {
  float r;
  asm("v_exp_f32 %0, %1" : "=v"(r) : "v"(x));
  return r;
}

// fp32 -> bf16 pre-pass: voxel (2097152 grp) then A (524288 grp)
__global__ __launch_bounds__(256) void convx2(const float* __restrict__ voxel,
                                              const float* __restrict__ A,
                                              unsigned short* __restrict__ xb,
                                              unsigned short* __restrict__ Ab) {
  for (int i = blockIdx.x * 256 + threadIdx.x; i < 2621440; i += gridDim.x * 256) {
    const float* src; unsigned short* dst; int j;
    if (i < 2097152) { j = i; src = voxel; dst = xb; }
    else { j = i - 2097152; src = A; dst = Ab; }
    float4 a = *(const float4*)(src + 8 * (size_t)j);
    float4 b = *(const float4*)(src + 8 * (size_t)j + 4);
    ushort8 o;
    o[0] = f2bf(a.x); o[1] = f2bf(a.y); o[2] = f2bf(a.z); o[3] = f2bf(a.w);
    o[4] = f2bf(b.x); o[5] = f2bf(b.y); o[6] = f2bf(b.z); o[7] = f2bf(b.w);
    *(ushort8*)(dst + 8 * (size_t)j) = o;
  }
}

// transpose+convert weights; block 512: cbbT[l][j] = cb[j][l] * log2e, zero asum
__global__ __launch_bounds__(256) void convw(const float* __restrict__ w_qkv,
                                             const float* __restrict__ w_proj,
                                             const float* __restrict__ cb,
                                             unsigned short* __restrict__ wqT,
                                             unsigned short* __restrict__ wpT,
                                             unsigned short* __restrict__ cbbT,
                                             float* __restrict__ asum) {
  int n = blockIdx.x, k = threadIdx.x;
  if (n < 256) wqT[n * 256 + k] = f2bf(w_qkv[(size_t)k * 768 + n]);
  else if (n < 512) wpT[(n - 256) * 256 + k] = f2bf(w_proj[(size_t)k * 256 + (n - 256)]);
  else {
    asum[k] = 0.f;
    if (k < 64) {
      for (int j = 0; j < 64; ++j)
        cbbT[k * 64 + j] = f2bf(cb[j * 64 + k] * 1.4426950408889634f);
    }
  }
}

// C[M,N] = A[M,K=256] @ BT[N,K]^T (+bias). MFMA bf16. Tile 128x128, 4 waves.
// K MUST be 256. Single-buffer LDS, 2-deep register prefetch, LDS-staged
// coalesced C writeout.
template <int ADD_BIAS, int C_BF16>
__global__ __launch_bounds__(256, 3) void gemm_mfma(const unsigned short* __restrict__ Ab,
                                                    const unsigned short* __restrict__ BT,
                                                    const float* __restrict__ bias,
                                                    void* __restrict__ Cv,
                                                    int N, int K, int lda) {
  __shared__ __align__(16) unsigned short smem[2][128][72];
  const int tid = threadIdx.x;
  int bx, by;
  if ((gridDim.y & 7) == 0) {
    int flat = blockIdx.y * gridDim.x + blockIdx.x;
    int xc = flat & 7, t = flat >> 3;
    int gx = gridDim.x, ypx = gridDim.y >> 3;
    bx = t % gx; by = xc * ypx + t / gx;
  } else { bx = blockIdx.x; by = blockIdx.y; }
  const int bn = bx * 128, bm = by * 128;
  const int lane = tid & 63;
  const int wv = tid >> 6;
  const int wm = wv & 1, wn = wv >> 1;
  const int m16 = lane & 15, quad = lane >> 4;

  const int srow = tid >> 1;
  const int scol = (tid & 1) * 32;

  const unsigned short* ga = Ab + (size_t)(bm + srow) * lda + scol;
  const unsigned short* gb = BT + (size_t)(bn + srow) * K + scol;

  ushort8 ra[2][4], rb[2][4];
#pragma unroll
  for (int kt = 0; kt < 2; ++kt)
#pragma unroll
    for (int i = 0; i < 4; ++i) {
      ra[kt][i] = *(const ushort8*)(ga + kt * 64 + 8 * i);
      rb[kt][i] = *(const ushort8*)(gb + kt * 64 + 8 * i);
    }

  f32x4 acc[4][4];
#pragma unroll
  for (int r = 0; r < 4; ++r)
#pragma unroll
    for (int c = 0; c < 4; ++c) acc[r][c] = (f32x4){0.f, 0.f, 0.f, 0.f};

#pragma unroll
  for (int kt = 0; kt < 4; ++kt) {
    const int sb = kt & 1;
    if (kt > 0) __syncthreads();
#pragma unroll
    for (int i = 0; i < 4; ++i) {
      *(ushort8*)&smem[0][srow][scol + 8 * i] = ra[sb][i];
      *(ushort8*)&smem[1][srow][scol + 8 * i] = rb[sb][i];
    }
    __syncthreads();
    if (kt < 2) {
#pragma unroll
      for (int i = 0; i < 4; ++i) {
        ra[sb][i] = *(const ushort8*)(ga + (kt + 2) * 64 + 8 * i);
        rb[sb][i] = *(const ushort8*)(gb + (kt + 2) * 64 + 8 * i);
      }
    }
#pragma unroll
    for (int ks = 0; ks < 64; ks += 32) {
      bf16x8 af[4], bf[4];
#pragma unroll
      for (int r = 0; r < 4; ++r)
        af[r] = *(const bf16x8*)&smem[0][wm * 64 + r * 16 + m16][ks + quad * 8];
#pragma unroll
      for (int c = 0; c < 4; ++c)
        bf[c] = *(const bf16x8*)&smem[1][wn * 64 + c * 16 + m16][ks + quad * 8];
#pragma unroll
      for (int r = 0; r < 4; ++r)
#pragma unroll
        for (int c = 0; c < 4; ++c)
          acc[r][c] = __builtin_amdgcn_mfma_f32_16x16x32_bf16(af[r], bf[c], acc[r][c], 0, 0, 0);
    }
  }

  float bv[4];
  if (ADD_BIAS) {
#pragma unroll
    for (int c = 0; c < 4; ++c) bv[c] = bias[bn + wn * 64 + c * 16 + m16];
  }
  const int lrD = tid >> 2, cch = (tid & 3) * 32;
  unsigned short* Csh = (unsigned short*)smem;
  float* Csf = (float*)smem;
#pragma unroll
  for (int p = 0; p < 2; ++p) {
    __syncthreads();
    if (wm == p) {
#pragma unroll
      for (int r = 0; r < 4; ++r) {
        int lr0 = r * 16 + quad * 4;
#pragma unroll
        for (int c = 0; c < 4; ++c) {
          int col = wn * 64 + c * 16 + m16;
#pragma unroll
          for (int i = 0; i < 4; ++i) {
            float v = acc[r][c][i] + (ADD_BIAS ? bv[c] : 0.f);
            if (C_BF16) Csh[(lr0 + i) * 136 + col] = f2bf(v);
            else Csf[(lr0 + i) * 132 + col] = v;
          }
        }
      }
    }
    __syncthreads();
    if (C_BF16) {
      unsigned short* gp = (unsigned short*)Cv + (size_t)(bm + p * 64 + lrD) * N + bn + cch;
      const unsigned short* sp = Csh + lrD * 136 + cch;
      ushort8 t0 = *(const ushort8*)(sp + 0);
      ushort8 t1 = *(const ushort8*)(sp + 8);
      ushort8 t2 = *(const ushort8*)(sp + 16);
      ushort8 t3 = *(const ushort8*)(sp + 24);
      *(ushort8*)(gp + 0) = t0;
      *(ushort8*)(gp + 8) = t1;
      *(ushort8*)(gp + 16) = t2;
      *(ushort8*)(gp + 24) = t3;
    } else {
      float* gp = (float*)Cv + (size_t)(bm + p * 64 + lrD) * N + bn + cch;
      const float* sp = Csf + lrD * 132 + cch;
      float4 t[8];
#pragma unroll
      for (int u = 0; u < 8; ++u) t[u] = *(const float4*)(sp + 4 * u);
#pragma unroll
      for (int u = 0; u < 8; ++u) *(float4*)(gp + 4 * u) = t[u];
    }
  }
}

// ---- pool X via MFMA: part[b][tch][cl 64][ch 256] over 256-token chunks ----
__global__ __launch_bounds__(256) void pool_mfma(const unsigned short* __restrict__ Ab,
                                                 const unsigned short* __restrict__ xb,
                                                 float* __restrict__ part) {
  __shared__ unsigned short At[64][40];
  __shared__ unsigned short Xt[128][40];
  const int tid = threadIdx.x;
  const int tch = blockIdx.x, cblk = blockIdx.y, b = blockIdx.z;
  const int w = tid >> 6, lane = tid & 63;
  const int m16 = lane & 15, quad = lane >> 4;
  const size_t row0 = (size_t)b * NTOK + (size_t)tch * 256;
  const int cb0 = cblk * 128;
  const int tokL = tid & 31, gA = tid >> 5;

  f32x4 acc[4][2];
#pragma unroll
  for (int r = 0; r < 4; ++r)
#pragma unroll
    for (int c = 0; c < 2; ++c) acc[r][c] = (f32x4){0.f, 0.f, 0.f, 0.f};

  ushort8 px[2], pa;
  auto loadG = [&](int t0) {
#pragma unroll
    for (int u = 0; u < 2; ++u) {
      int idx = tid + u * 256;
      int tok = idx & 31, g = idx >> 5;
      px[u] = *(const ushort8*)(xb + (row0 + t0 + tok) * 256 + cb0 + g * 8);
    }
    pa = *(const ushort8*)(Ab + (row0 + t0 + tokL) * 64 + gA * 8);
  };
  loadG(0);

  for (int ks = 0; ks < 8; ++ks) {
    __syncthreads();
#pragma unroll
    for (int u = 0; u < 2; ++u) {
      int idx = tid + u * 256;
      int tok = idx & 31, g = idx >> 5;
#pragma unroll
      for (int i = 0; i < 8; ++i) Xt[g * 8 + i][tok] = (unsigned short)px[u][i];
    }
#pragma unroll
    for (int i = 0; i < 8; ++i) At[gA * 8 + i][tokL] = (unsigned short)pa[i];
    __syncthreads();
    if (ks + 1 < 8) loadG((ks + 1) * 32);
    bf16x8 af[4], bfr[2];
#pragma unroll
    for (int r = 0; r < 4; ++r) af[r] = *(const bf16x8*)&At[r * 16 + m16][quad * 8];
#pragma unroll
    for (int c = 0; c < 2; ++c) bfr[c] = *(const bf16x8*)&Xt[w * 32 + c * 16 + m16][quad * 8];
#pragma unroll
    for (int r = 0; r < 4; ++r)
#pragma unroll
      for (int c = 0; c < 2; ++c)
        acc[r][c] = __builtin_amdgcn_mfma_f32_16x16x32_bf16(af[r], bfr[c], acc[r][c], 0, 0, 0);
  }

  float* pp = part + ((size_t)(b * 64 + tch) * 64) * 256 + cb0;
#pragma unroll
  for (int r = 0; r < 4; ++r)
#pragma unroll
    for (int c = 0; c < 2; ++c)
#pragma unroll
      for (int i = 0; i < 4; ++i) {
        int cl = r * 16 + quad * 4 + i;
        int ch = w * 32 + c * 16 + m16;
        pp[(size_t)cl * 256 + ch] = acc[r][c][i];
      }
}

// fused: reduce 64 chunks -> pooledX row (f32, /denom) in LDS, then fp32
// K/V mini-GEMM vs w_qkv[:,256:768]. One block per (b,cl). kcb scaled by
// d^-0.5 * log2e (exp2-domain softmax); vcbT unscaled.
__global__ __launch_bounds__(256) void pool2kv(const float* __restrict__ part,
                                               const float* __restrict__ asum,
                                               const float* __restrict__ w_qkv,
                                               unsigned short* __restrict__ kcb,
                                               unsigned short* __restrict__ vcbT) {
  __shared__ float px[256];
  const int bc = blockIdx.x;  // b*64 + cl
  const int b = bc >> 6, cl = bc & 63;
  const int c = threadIdx.x;
  const float* pp = part + ((size_t)(b * 64) * 64 + cl) * 256 + c;
  float s = 0.f;
#pragma unroll 4
  for (int t = 0; t < 64; ++t) s += pp[(size_t)t * 16384];
  float denom = asum[b * 64 + cl] + 1e-8f;
  px[c] = s / denom;
  __syncthreads();
  float accK = 0.f, accV = 0.f;
#pragma unroll 8
  for (int k = 0; k < 256; ++k) {
    float x = px[k];
    accK = fmaf(x, w_qkv[(size_t)k * 768 + 256 + c], accK);
    accV = fmaf(x, w_qkv[(size_t)k * 768 + 512 + c], accV);
  }
  int h = c >> 5, d = c & 31;
  kcb[(((size_t)b * 8 + h) * 64 + cl) * 32 + d] =
      f2bf(accK * (0.17677669529663687f * 1.4426950408889634f));
  vcbT[(((size_t)b * 8 + h) * 32 + d) * 64 + cl] = f2bf(accV);
}

__global__ __launch_bounds__(256) void asum_kernel(const float* __restrict__ A,
                                                   float* __restrict__ asum) {
  __shared__ float red[4][64];
  const int ch = blockIdx.x, b = blockIdx.y;
  const int jq = threadIdx.x >> 6, k = threadIdx.x & 63;
  const size_t row0 = (size_t)b * NTOK + (size_t)ch * 256;
  const float* ap = A + (row0 + jq) * 64 + k;
  float s = 0.f;
#pragma unroll 4
  for (int j = 0; j < 64; ++j) s += ap[(size_t)j * 256];
  red[jq][k] = s;
  __syncthreads();
  if (threadIdx.x < 64) {
    float v = red[0][k] + red[1][k] + red[2][k] + red[3][k];
    atomicAdd(&asum[b * 64 + k], v);
  }
}

// ---- fused attention v3: 64 tokens x ALL 8 heads per block, ZERO barriers.
// All MFMA operands loaded global->reg in fragment layout (kcb/vcbT/cbbT are
// L2-resident); LDS holds only P (wave-local transpose). bias = A@cbT MFMA'd
// once into regs. Softmax in exp2 domain (tables pre-scaled by log2e). ----
__global__ __launch_bounds__(256) void attn_mfma(const unsigned short* __restrict__ Ab,
                                                 unsigned short* __restrict__ qb,
                                                 const unsigned short* __restrict__ kcb,
                                                 const unsigned short* __restrict__ vcbT,
                                                 const unsigned short* __restrict__ cbbT) {
  __shared__ __align__(16) unsigned short PA[64 * 72];  // 9216 B

  const int tid = threadIdx.x;
  const int nb = blockIdx.x, b = blockIdx.z;
  const int w = tid >> 6, lane = tid & 63;
  const int m16 = lane & 15, quad = lane >> 4;
  const size_t row0 = (size_t)b * NTOK + (size_t)nb * 64;
  const int rA = w * 16 + m16;          // this lane's fragment row (A-operand)
  const size_t bh8 = (size_t)b * 8;

  // ---- bias = A @ cbT (K=64) straight from global ----
  f32x4 bacc[4];
#pragma unroll
  for (int nt = 0; nt < 4; ++nt) bacc[nt] = (f32x4){0.f, 0.f, 0.f, 0.f};
#pragma unroll
  for (int ks = 0; ks < 2; ++ks) {
    bf16x8 aA = *(const bf16x8*)(Ab + (row0 + rA) * 64 + ks * 32 + quad * 8);
#pragma unroll
    for (int nt = 0; nt < 4; ++nt) {
      bf16x8 cbf = *(const bf16x8*)(cbbT + (nt * 16 + m16) * 64 + ks * 32 + quad * 8);
      bacc[nt] = __builtin_amdgcn_mfma_f32_16x16x32_bf16(aA, cbf, bacc[nt], 0, 0, 0);
    }
  }

  for (int h = 0; h < 8; ++h) {
    // ---- fragment loads (global; kc/vt from L2) ----
    bf16x8 qf = *(const bf16x8*)(qb + (row0 + rA) * 256 + h * 32 + quad * 8);
    bf16x8 kcf[4];
#pragma unroll
    for (int nt = 0; nt < 4; ++nt)
      kcf[nt] = *(const bf16x8*)(kcb + ((bh8 + h) * 64 + nt * 16 + m16) * 32 + quad * 8);
    bf16x8 vtf[2][2];
#pragma unroll
    for (int nt2 = 0; nt2 < 2; ++nt2)
#pragma unroll
      for (int kc2 = 0; kc2 < 2; ++kc2)
        vtf[nt2][kc2] = *(const bf16x8*)(vcbT + ((bh8 + h) * 32 + nt2 * 16 + m16) * 64 +
                                         kc2 * 32 + quad * 8);

    // ---- scores (log2-domain) = bias + q @ kc^T ----
    f32x4 acc[4];
#pragma unroll
    for (int nt = 0; nt < 4; ++nt) {
      acc[nt] = bacc[nt];
      acc[nt] = __builtin_amdgcn_mfma_f32_16x16x32_bf16(qf, kcf[nt], acc[nt], 0, 0, 0);
    }

    // ---- softmax: row = quad*4+i, 64 cols = nt x m16; exp2 ----
    f32x4 mxv, sv;
#pragma unroll
    for (int i = 0; i < 4; ++i)
      mxv[i] = fmaxf(fmaxf(acc[0][i], acc[1][i]), fmaxf(acc[2][i], acc[3][i]));
#pragma unroll
    for (int msk = 1; msk < 16; msk <<= 1)
#pragma unroll
      for (int i = 0; i < 4; ++i) mxv[i] = fmaxf(mxv[i], __shfl_xor(mxv[i], msk));
#pragma unroll
    for (int i = 0; i < 4; ++i) sv[i] = 0.f;
#pragma unroll
    for (int nt = 0; nt < 4; ++nt)
#pragma unroll
      for (int i = 0; i < 4; ++i) {
        float e = exp2_fast(acc[nt][i] - mxv[i]);
        acc[nt][i] = e;
        sv[i] += e;
      }
#pragma unroll
    for (int msk = 1; msk < 16; msk <<= 1)
#pragma unroll
      for (int i = 0; i < 4; ++i) sv[i] += __shfl_xor(sv[i], msk);
#pragma unroll
    for (int i = 0; i < 4; ++i) sv[i] = 1.f / sv[i];

    // P -> LDS (wave-local rows; same-wave RAW handled by lgkmcnt)
#pragma unroll
    for (int nt = 0; nt < 4; ++nt)
#pragma unroll
      for (int i = 0; i < 4; ++i)
        PA[(w * 16 + quad * 4 + i) * 72 + nt * 16 + m16] = f2bf(acc[nt][i] * sv[i]);

    // ---- x = P @ vcT ----
    f32x4 acc2[2];
#pragma unroll
    for (int nt2 = 0; nt2 < 2; ++nt2) acc2[nt2] = (f32x4){0.f, 0.f, 0.f, 0.f};
#pragma unroll
    for (int kc2 = 0; kc2 < 2; ++kc2) {
      bf16x8 pf = *(const bf16x8*)&PA[rA * 72 + kc2 * 32 + quad * 8];
#pragma unroll
      for (int nt2 = 0; nt2 < 2; ++nt2)
        acc2[nt2] = __builtin_amdgcn_mfma_f32_16x16x32_bf16(pf, vtf[nt2][kc2], acc2[nt2], 0, 0, 0);
    }

    // x overwrites Q slot (cols h*32.., already consumed this iteration)
#pragma unroll
    for (int nt2 = 0; nt2 < 2; ++nt2)
#pragma unroll
      for (int i = 0; i < 4; ++i)
        qb[(row0 + w * 16 + quad * 4 + i) * 256 + h * 32 + nt2 * 16 + m16] =
            f2bf(acc2[nt2][i]);
  }
}

extern "C" void kernel_launch(void* const* d_in, const int* in_sizes, int n_in,
                              void* d_out, int out_size, void* d_ws, size_t ws_size,
                              hipStream_t stream) {
  const float* voxel  = (const float*)d_in[0];
  const float* A      = (const float*)d_in[1];
  const float* w_qkv  = (const float*)d_in[2];
  const float* w_proj = (const float*)d_in[3];
  const float* b_proj = (const float*)d_in[4];
  const float* cb     = (const float*)d_in[5];
  float* out = (float*)d_out;
  (void)in_sizes; (void)n_in; (void)out_size; (void)ws_size;

  // ws layout (byte offsets / sizes):
  // qb        0         33554432
  // xb        33554432  33554432
  // part      67108864  16777216
  // asum      83886080  1024
  // wqT       84149248  131072
  // wpT       84280320  131072
  // kcb       84411392  131072   (4*8*64*32 shorts)
  // vcbT      84542464  131072
  // cbbT      84673536  8192
  char* wsb = (char*)d_ws;
  unsigned short* qb       = (unsigned short*)wsb;
  unsigned short* xb       = (unsigned short*)(wsb + 33554432);
  float* part              = (float*)(wsb + 67108864);
  float* asum              = (float*)(wsb + 83886080);
  unsigned short* wqT      = (unsigned short*)(wsb + 84149248);
  unsigned short* wpT      = (unsigned short*)(wsb + 84280320);
  unsigned short* kcb      = (unsigned short*)(wsb + 84411392);
  unsigned short* vcbT     = (unsigned short*)(wsb + 84542464);
  unsigned short* cbbT     = (unsigned short*)(wsb + 84673536);
  // Ab (bf16 A, 8 MB) parked in d_out: dead before the final GEMM writes out
  unsigned short* Ab = (unsigned short*)d_out;

  convw<<<513, 256, 0, stream>>>(w_qkv, w_proj, cb, wqT, wpT, cbbT, asum);
  convx2<<<2048, 256, 0, stream>>>(voxel, A, xb, Ab);

  // Q only: qb(bf16) = xb @ Wq
  gemm_mfma<0, 1><<<dim3(2, 512), 256, 0, stream>>>(xb, wqT, nullptr, qb,
                                                    256, 256, 256);

  asum_kernel<<<dim3(64, BATCH), 256, 0, stream>>>(A, asum);
  // pooledX = A^T @ X (per 256-token chunk partials)
  pool_mfma<<<dim3(64, 2, BATCH), 256, 0, stream>>>(Ab, xb, part);
  // fused reduce + fp32 K/V mini-GEMM
  pool2kv<<<256, 256, 0, stream>>>(part, asum, w_qkv, kcb, vcbT);

  // fused attention: 64 tokens x 8 heads per block, barrier-free
  attn_mfma<<<dim3(NTOK / 64, 1, BATCH), 256, 0, stream>>>(Ab, qb, kcb, vcbT, cbbT);

  // out = x @ w_proj + b_proj (x bf16 in qb, lda 256)
  gemm_mfma<1, 0><<<dim3(2, 512), 256, 0, stream>>>(qb, wpT, b_proj, out,
                                                    256, 256, 256);
}

// Round 8
// 271.599 us; speedup vs baseline: 1.0225x; 1.0225x over previous
//
#include <hip/hip_runtime.h>

#define NTOK 16384
#define BATCH 4

typedef __attribute__((ext_vector_type(8))) short bf16x8;
typedef __attribute__((ext_vector_type(8))) unsigned short ushort8;
typedef __attribute__((ext_vector_type(4))) float f32x4;

__device__ __forceinline__ unsigned short f2bf(float f) {
  union { float f; unsigned int u; } c; c.f = f;
  unsigned int r = c.u + 0x7fff + ((c.u >> 16) & 1);  // RTN-even
  return (unsigned short)(r >> 16);
}

__device__ __forceinline__ float exp2_fast(float x) {
  float r;
  asm("v_exp_f32 %0, %1" : "=v"(r) : "v"(x));
  return r;
}

// fp32 -> bf16 pre-pass: voxel (2097152 grp) then A (524288 grp)
__global__ __launch_bounds__(256) void convx2(const float* __restrict__ voxel,
                                              const float* __restrict__ A,
                                              unsigned short* __restrict__ xb,
                                              unsigned short* __restrict__ Ab) {
  for (int i = blockIdx.x * 256 + threadIdx.x; i < 2621440; i += gridDim.x * 256) {
    const float* src; unsigned short* dst; int j;
    if (i < 2097152) { j = i; src = voxel; dst = xb; }
    else { j = i - 2097152; src = A; dst = Ab; }
    float4 a = *(const float4*)(src + 8 * (size_t)j);
    float4 b = *(const float4*)(src + 8 * (size_t)j + 4);
    ushort8 o;
    o[0] = f2bf(a.x); o[1] = f2bf(a.y); o[2] = f2bf(a.z); o[3] = f2bf(a.w);
    o[4] = f2bf(b.x); o[5] = f2bf(b.y); o[6] = f2bf(b.z); o[7] = f2bf(b.w);
    *(ushort8*)(dst + 8 * (size_t)j) = o;
  }
}

// transpose+convert weights; block 512: cbbT[l][j] = cb[j][l] * log2e
__global__ __launch_bounds__(256) void convw(const float* __restrict__ w_qkv,
                                             const float* __restrict__ w_proj,
                                             const float* __restrict__ cb,
                                             unsigned short* __restrict__ wqT,
                                             unsigned short* __restrict__ wpT,
                                             unsigned short* __restrict__ cbbT) {
  int n = blockIdx.x, k = threadIdx.x;
  if (n < 256) wqT[n * 256 + k] = f2bf(w_qkv[(size_t)k * 768 + n]);
  else if (n < 512) wpT[(n - 256) * 256 + k] = f2bf(w_proj[(size_t)k * 256 + (n - 256)]);
  else if (k < 64) {
    for (int j = 0; j < 64; ++j)
      cbbT[k * 64 + j] = f2bf(cb[j * 64 + k] * 1.4426950408889634f);
  }
}

// C[M,N] = A[M,K=256] @ BT[N,K]^T (+bias). MFMA bf16. Tile 128x128, 4 waves.
// K MUST be 256. Single-buffer LDS, 2-deep register prefetch, LDS-staged
// coalesced C writeout.
template <int ADD_BIAS, int C_BF16>
__global__ __launch_bounds__(256, 3) void gemm_mfma(const unsigned short* __restrict__ Ab,
                                                    const unsigned short* __restrict__ BT,
                                                    const float* __restrict__ bias,
                                                    void* __restrict__ Cv,
                                                    int N, int K, int lda) {
  __shared__ __align__(16) unsigned short smem[2][128][72];
  const int tid = threadIdx.x;
  int bx, by;
  if ((gridDim.y & 7) == 0) {
    int flat = blockIdx.y * gridDim.x + blockIdx.x;
    int xc = flat & 7, t = flat >> 3;
    int gx = gridDim.x, ypx = gridDim.y >> 3;
    bx = t % gx; by = xc * ypx + t / gx;
  } else { bx = blockIdx.x; by = blockIdx.y; }
  const int bn = bx * 128, bm = by * 128;
  const int lane = tid & 63;
  const int wv = tid >> 6;
  const int wm = wv & 1, wn = wv >> 1;
  const int m16 = lane & 15, quad = lane >> 4;

  const int srow = tid >> 1;
  const int scol = (tid & 1) * 32;

  const unsigned short* ga = Ab + (size_t)(bm + srow) * lda + scol;
  const unsigned short* gb = BT + (size_t)(bn + srow) * K + scol;

  ushort8 ra[2][4], rb[2][4];
#pragma unroll
  for (int kt = 0; kt < 2; ++kt)
#pragma unroll
    for (int i = 0; i < 4; ++i) {
      ra[kt][i] = *(const ushort8*)(ga + kt * 64 + 8 * i);
      rb[kt][i] = *(const ushort8*)(gb + kt * 64 + 8 * i);
    }

  f32x4 acc[4][4];
#pragma unroll
  for (int r = 0; r < 4; ++r)
#pragma unroll
    for (int c = 0; c < 4; ++c) acc[r][c] = (f32x4){0.f, 0.f, 0.f, 0.f};

#pragma unroll
  for (int kt = 0; kt < 4; ++kt) {
    const int sb = kt & 1;
    if (kt > 0) __syncthreads();
#pragma unroll
    for (int i = 0; i < 4; ++i) {
      *(ushort8*)&smem[0][srow][scol + 8 * i] = ra[sb][i];
      *(ushort8*)&smem[1][srow][scol + 8 * i] = rb[sb][i];
    }
    __syncthreads();
    if (kt < 2) {
#pragma unroll
      for (int i = 0; i < 4; ++i) {
        ra[sb][i] = *(const ushort8*)(ga + (kt + 2) * 64 + 8 * i);
        rb[sb][i] = *(const ushort8*)(gb + (kt + 2) * 64 + 8 * i);
      }
    }
#pragma unroll
    for (int ks = 0; ks < 64; ks += 32) {
      bf16x8 af[4], bf[4];
#pragma unroll
      for (int r = 0; r < 4; ++r)
        af[r] = *(const bf16x8*)&smem[0][wm * 64 + r * 16 + m16][ks + quad * 8];
#pragma unroll
      for (int c = 0; c < 4; ++c)
        bf[c] = *(const bf16x8*)&smem[1][wn * 64 + c * 16 + m16][ks + quad * 8];
#pragma unroll
      for (int r = 0; r < 4; ++r)
#pragma unroll
        for (int c = 0; c < 4; ++c)
          acc[r][c] = __builtin_amdgcn_mfma_f32_16x16x32_bf16(af[r], bf[c], acc[r][c], 0, 0, 0);
    }
  }

  float bv[4];
  if (ADD_BIAS) {
#pragma unroll
    for (int c = 0; c < 4; ++c) bv[c] = bias[bn + wn * 64 + c * 16 + m16];
  }
  const int lrD = tid >> 2, cch = (tid & 3) * 32;
  unsigned short* Csh = (unsigned short*)smem;
  float* Csf = (float*)smem;
#pragma unroll
  for (int p = 0; p < 2; ++p) {
    __syncthreads();
    if (wm == p) {
#pragma unroll
      for (int r = 0; r < 4; ++r) {
        int lr0 = r * 16 + quad * 4;
#pragma unroll
        for (int c = 0; c < 4; ++c) {
          int col = wn * 64 + c * 16 + m16;
#pragma unroll
          for (int i = 0; i < 4; ++i) {
            float v = acc[r][c][i] + (ADD_BIAS ? bv[c] : 0.f);
            if (C_BF16) Csh[(lr0 + i) * 136 + col] = f2bf(v);
            else Csf[(lr0 + i) * 132 + col] = v;
          }
        }
      }
    }
    __syncthreads();
    if (C_BF16) {
      unsigned short* gp = (unsigned short*)Cv + (size_t)(bm + p * 64 + lrD) * N + bn + cch;
      const unsigned short* sp = Csh + lrD * 136 + cch;
      ushort8 t0 = *(const ushort8*)(sp + 0);
      ushort8 t1 = *(const ushort8*)(sp + 8);
      ushort8 t2 = *(const ushort8*)(sp + 16);
      ushort8 t3 = *(const ushort8*)(sp + 24);
      *(ushort8*)(gp + 0) = t0;
      *(ushort8*)(gp + 8) = t1;
      *(ushort8*)(gp + 16) = t2;
      *(ushort8*)(gp + 24) = t3;
    } else {
      float* gp = (float*)Cv + (size_t)(bm + p * 64 + lrD) * N + bn + cch;
      const float* sp = Csf + lrD * 132 + cch;
      float4 t[8];
#pragma unroll
      for (int u = 0; u < 8; ++u) t[u] = *(const float4*)(sp + 4 * u);
#pragma unroll
      for (int u = 0; u < 8; ++u) *(float4*)(gp + 4 * u) = t[u];
    }
  }
}

// ---- pool X via MFMA: part[b][tch][cl 64][ch 256] over 256-token chunks.
// cblk==0 blocks also compute chunk A-sums (A^T @ ones) -> asump[b][tch][cl]
// (race-free overwrite; replaces the separate asum kernel + atomics). ----
__global__ __launch_bounds__(256) void pool_mfma(const unsigned short* __restrict__ Ab,
                                                 const unsigned short* __restrict__ xb,
                                                 float* __restrict__ part,
                                                 float* __restrict__ asump) {
  __shared__ unsigned short At[64][40];
  __shared__ unsigned short Xt[128][40];
  const int tid = threadIdx.x;
  const int tch = blockIdx.x, cblk = blockIdx.y, b = blockIdx.z;
  const int w = tid >> 6, lane = tid & 63;
  const int m16 = lane & 15, quad = lane >> 4;
  const size_t row0 = (size_t)b * NTOK + (size_t)tch * 256;
  const int cb0 = cblk * 128;
  const int tokL = tid & 31, gA = tid >> 5;

  f32x4 acc[4][2];
#pragma unroll
  for (int r = 0; r < 4; ++r)
#pragma unroll
    for (int c = 0; c < 2; ++c) acc[r][c] = (f32x4){0.f, 0.f, 0.f, 0.f};
  f32x4 acc1[4];
#pragma unroll
  for (int r = 0; r < 4; ++r) acc1[r] = (f32x4){0.f, 0.f, 0.f, 0.f};
  bf16x8 onesv;
#pragma unroll
  for (int i = 0; i < 8; ++i) onesv[i] = (short)0x3F80;  // bf16 1.0

  ushort8 px[2], pa;
  auto loadG = [&](int t0) {
#pragma unroll
    for (int u = 0; u < 2; ++u) {
      int idx = tid + u * 256;
      int tok = idx & 31, g = idx >> 5;
      px[u] = *(const ushort8*)(xb + (row0 + t0 + tok) * 256 + cb0 + g * 8);
    }
    pa = *(const ushort8*)(Ab + (row0 + t0 + tokL) * 64 + gA * 8);
  };
  loadG(0);

  for (int ks = 0; ks < 8; ++ks) {
    __syncthreads();
#pragma unroll
    for (int u = 0; u < 2; ++u) {
      int idx = tid + u * 256;
      int tok = idx & 31, g = idx >> 5;
#pragma unroll
      for (int i = 0; i < 8; ++i) Xt[g * 8 + i][tok] = (unsigned short)px[u][i];
    }
#pragma unroll
    for (int i = 0; i < 8; ++i) At[gA * 8 + i][tokL] = (unsigned short)pa[i];
    __syncthreads();
    if (ks + 1 < 8) loadG((ks + 1) * 32);
    bf16x8 af[4], bfr[2];
#pragma unroll
    for (int r = 0; r < 4; ++r) af[r] = *(const bf16x8*)&At[r * 16 + m16][quad * 8];
#pragma unroll
    for (int c = 0; c < 2; ++c) bfr[c] = *(const bf16x8*)&Xt[w * 32 + c * 16 + m16][quad * 8];
#pragma unroll
    for (int r = 0; r < 4; ++r)
#pragma unroll
      for (int c = 0; c < 2; ++c)
        acc[r][c] = __builtin_amdgcn_mfma_f32_16x16x32_bf16(af[r], bfr[c], acc[r][c], 0, 0, 0);
    if (cblk == 0) {
#pragma unroll
      for (int r = 0; r < 4; ++r)
        acc1[r] = __builtin_amdgcn_mfma_f32_16x16x32_bf16(af[r], onesv, acc1[r], 0, 0, 0);
    }
  }

  float* pp = part + ((size_t)(b * 64 + tch) * 64) * 256 + cb0;
#pragma unroll
  for (int r = 0; r < 4; ++r)
#pragma unroll
    for (int c = 0; c < 2; ++c)
#pragma unroll
      for (int i = 0; i < 4; ++i) {
        int cl = r * 16 + quad * 4 + i;
        int ch = w * 32 + c * 16 + m16;
        pp[(size_t)cl * 256 + ch] = acc[r][c][i];
      }
  if (cblk == 0 && tid < 64 && m16 == 0) {
    float* ap = asump + ((size_t)(b * 64 + tch)) * 64;
#pragma unroll
    for (int r = 0; r < 4; ++r)
#pragma unroll
      for (int i = 0; i < 4; ++i)
        ap[r * 16 + quad * 4 + i] = acc1[r][i];
  }
}

// fused: reduce 64 chunks of part -> pooledX row (f32), wave-reduce asump ->
// denom, then fp32 K/V mini-GEMM vs w_qkv[:,256:768]. One block per (b,cl).
// kcb scaled by d^-0.5 * log2e (exp2-domain softmax); vcbT unscaled.
__global__ __launch_bounds__(256) void pool2kv(const float* __restrict__ part,
                                               const float* __restrict__ asump,
                                               const float* __restrict__ w_qkv,
                                               unsigned short* __restrict__ kcb,
                                               unsigned short* __restrict__ vcbT) {
  __shared__ float px[256];
  __shared__ float dsh;
  const int bc = blockIdx.x;  // b*64 + cl
  const int b = bc >> 6, cl = bc & 63;
  const int c = threadIdx.x;
  if (c < 64) {
    float av = asump[((size_t)(b * 64) + c) * 64 + cl];
#pragma unroll
    for (int msk = 1; msk < 64; msk <<= 1) av += __shfl_xor(av, msk);
    if (c == 0) dsh = av + 1e-8f;
  }
  const float* pp = part + ((size_t)(b * 64) * 64 + cl) * 256 + c;
  float s = 0.f;
#pragma unroll 4
  for (int t = 0; t < 64; ++t) s += pp[(size_t)t * 16384];
  px[c] = s;  // raw; denom applied at the end (same math, one divide)
  __syncthreads();
  float accK = 0.f, accV = 0.f;
#pragma unroll 8
  for (int k = 0; k < 256; ++k) {
    float x = px[k];
    accK = fmaf(x, w_qkv[(size_t)k * 768 + 256 + c], accK);
    accV = fmaf(x, w_qkv[(size_t)k * 768 + 512 + c], accV);
  }
  float inv = 1.f / dsh;
  int h = c >> 5, d = c & 31;
  kcb[(((size_t)b * 8 + h) * 64 + cl) * 32 + d] =
      f2bf(accK * inv * (0.17677669529663687f * 1.4426950408889634f));
  vcbT[(((size_t)b * 8 + h) * 32 + d) * 64 + cl] = f2bf(accV * inv);
}

// ---- fused attention v4: 64 tokens x 4 heads per block (grid 2048 -> 8
// blocks/CU TLP). x -> SEPARATE buffer xout (no loop-carried alias with qb ->
// loads pipeline across heads). P stored UNNORMALIZED (1/l folded into PV
// output; sum-reduce overlaps P writes). x writeout staged through wave-local
// LDS -> coalesced ushort8 stores. Zero barriers. exp2-domain softmax. ----
__global__ __launch_bounds__(256) void attn_mfma(const unsigned short* __restrict__ Ab,
                                                 const unsigned short* __restrict__ qb,
                                                 unsigned short* __restrict__ xout,
                                                 const unsigned short* __restrict__ kcb,
                                                 const unsigned short* __restrict__ vcbT,
                                                 const unsigned short* __restrict__ cbbT) {
  __shared__ __align__(16) unsigned short PA[64 * 72];  // P tile
  __shared__ __align__(16) unsigned short XO[64 * 36];  // x staging

  const int tid = threadIdx.x;
  const int nb = blockIdx.x, hq = blockIdx.y, b = blockIdx.z;
  const int h0 = hq * 4;
  const int w = tid >> 6, lane = tid & 63;
  const int m16 = lane & 15, quad = lane >> 4;
  const size_t row0 = (size_t)b * NTOK + (size_t)nb * 64;
  const int rA = w * 16 + m16;
  const size_t bh8 = (size_t)b * 8;
  const int l4 = lane >> 2, s3 = lane & 3;

  // ---- bias = A @ cbT (K=64) straight from global ----
  f32x4 bacc[4];
#pragma unroll
  for (int nt = 0; nt < 4; ++nt) bacc[nt] = (f32x4){0.f, 0.f, 0.f, 0.f};
#pragma unroll
  for (int ks = 0; ks < 2; ++ks) {
    bf16x8 aA = *(const bf16x8*)(Ab + (row0 + rA) * 64 + ks * 32 + quad * 8);
#pragma unroll
    for (int nt = 0; nt < 4; ++nt) {
      bf16x8 cbf = *(const bf16x8*)(cbbT + (nt * 16 + m16) * 64 + ks * 32 + quad * 8);
      bacc[nt] = __builtin_amdgcn_mfma_f32_16x16x32_bf16(aA, cbf, bacc[nt], 0, 0, 0);
    }
  }

#pragma unroll
  for (int hh = 0; hh < 4; ++hh) {
    const int h = h0 + hh;
    bf16x8 qf = *(const bf16x8*)(qb + (row0 + rA) * 256 + h * 32 + quad * 8);
    bf16x8 kcf[4];
#pragma unroll
    for (int nt = 0; nt < 4; ++nt)
      kcf[nt] = *(const bf16x8*)(kcb + ((bh8 + h) * 64 + nt * 16 + m16) * 32 + quad * 8);
    bf16x8 vtf[2][2];
#pragma unroll
    for (int nt2 = 0; nt2 < 2; ++nt2)
#pragma unroll
      for (int kc2 = 0; kc2 < 2; ++kc2)
        vtf[nt2][kc2] = *(const bf16x8*)(vcbT + ((bh8 + h) * 32 + nt2 * 16 + m16) * 64 +
                                         kc2 * 32 + quad * 8);

    // scores (log2 domain) = bias + q @ kc^T
    f32x4 acc[4];
#pragma unroll
    for (int nt = 0; nt < 4; ++nt)
      acc[nt] = __builtin_amdgcn_mfma_f32_16x16x32_bf16(qf, kcf[nt], bacc[nt], 0, 0, 0);

    // softmax: row = quad*4+i, 64 cols = nt x m16
    f32x4 mxv, sv;
#pragma unroll
    for (int i = 0; i < 4; ++i)
      mxv[i] = fmaxf(fmaxf(acc[0][i], acc[1][i]), fmaxf(acc[2][i], acc[3][i]));
#pragma unroll
    for (int msk = 1; msk < 16; msk <<= 1)
#pragma unroll
      for (int i = 0; i < 4; ++i) mxv[i] = fmaxf(mxv[i], __shfl_xor(mxv[i], msk));
#pragma unroll
    for (int i = 0; i < 4; ++i) sv[i] = 0.f;
#pragma unroll
    for (int nt = 0; nt < 4; ++nt)
#pragma unroll
      for (int i = 0; i < 4; ++i) {
        float e = exp2_fast(acc[nt][i] - mxv[i]);
        acc[nt][i] = e;
        sv[i] += e;
      }
    // P (unnormalized, <=1) -> LDS immediately; sum-reduce overlaps
#pragma unroll
    for (int nt = 0; nt < 4; ++nt)
#pragma unroll
      for (int i = 0; i < 4; ++i)
        PA[(w * 16 + quad * 4 + i) * 72 + nt * 16 + m16] = f2bf(acc[nt][i]);
#pragma unroll
    for (int msk = 1; msk < 16; msk <<= 1)
#pragma unroll
      for (int i = 0; i < 4; ++i) sv[i] += __shfl_xor(sv[i], msk);
#pragma unroll
    for (int i = 0; i < 4; ++i) sv[i] = 1.f / sv[i];

    // x = (P @ vcT) * (1/l)
    f32x4 acc2[2];
#pragma unroll
    for (int nt2 = 0; nt2 < 2; ++nt2) acc2[nt2] = (f32x4){0.f, 0.f, 0.f, 0.f};
#pragma unroll
    for (int kc2 = 0; kc2 < 2; ++kc2) {
      bf16x8 pf = *(const bf16x8*)&PA[rA * 72 + kc2 * 32 + quad * 8];
#pragma unroll
      for (int nt2 = 0; nt2 < 2; ++nt2)
        acc2[nt2] = __builtin_amdgcn_mfma_f32_16x16x32_bf16(pf, vtf[nt2][kc2], acc2[nt2], 0, 0, 0);
    }

    // stage x in wave-local LDS, then coalesced 16B stores
#pragma unroll
    for (int nt2 = 0; nt2 < 2; ++nt2)
#pragma unroll
      for (int i = 0; i < 4; ++i)
        XO[(w * 16 + quad * 4 + i) * 36 + nt2 * 16 + m16] = f2bf(acc2[nt2][i] * sv[i]);
    ushort8 xv = *(const ushort8*)&XO[(w * 16 + l4) * 36 + s3 * 8];
    *(ushort8*)(xout + (row0 + w * 16 + l4) * 256 + h * 32 + s3 * 8) = xv;
  }
}

extern "C" void kernel_launch(void* const* d_in, const int* in_sizes, int n_in,
                              void* d_out, int out_size, void* d_ws, size_t ws_size,
                              hipStream_t stream) {
  const float* voxel  = (const float*)d_in[0];
  const float* A      = (const float*)d_in[1];
  const float* w_qkv  = (const float*)d_in[2];
  const float* w_proj = (const float*)d_in[3];
  const float* b_proj = (const float*)d_in[4];
  const float* cb     = (const float*)d_in[5];
  float* out = (float*)d_out;
  (void)in_sizes; (void)n_in; (void)out_size; (void)ws_size;

  // ws layout (byte offsets / sizes):
  // qb      0         33554432
  // xb      33554432  33554432   (X bf16; overwritten with x by attn)
  // part    67108864  16777216
  // asump   83886080  65536      (4*64*64 f32 chunk A-sums)
  // wqT     83951616  131072
  // wpT     84082688  131072
  // kcb     84213760  131072
  // vcbT    84344832  131072
  // cbbT    84475904  8192
  char* wsb = (char*)d_ws;
  unsigned short* qb       = (unsigned short*)wsb;
  unsigned short* xb       = (unsigned short*)(wsb + 33554432);
  float* part              = (float*)(wsb + 67108864);
  float* asump             = (float*)(wsb + 83886080);
  unsigned short* wqT      = (unsigned short*)(wsb + 83951616);
  unsigned short* wpT      = (unsigned short*)(wsb + 84082688);
  unsigned short* kcb      = (unsigned short*)(wsb + 84213760);
  unsigned short* vcbT     = (unsigned short*)(wsb + 84344832);
  unsigned short* cbbT     = (unsigned short*)(wsb + 84475904);
  // Ab (bf16 A, 8 MB) parked in d_out: dead before the final GEMM writes out
  unsigned short* Ab = (unsigned short*)d_out;

  convw<<<513, 256, 0, stream>>>(w_qkv, w_proj, cb, wqT, wpT, cbbT);
  convx2<<<2048, 256, 0, stream>>>(voxel, A, xb, Ab);

  // Q only: qb(bf16) = xb @ Wq
  gemm_mfma<0, 1><<<dim3(2, 512), 256, 0, stream>>>(xb, wqT, nullptr, qb,
                                                    256, 256, 256);

  // pooledX partials = A^T @ X per 256-token chunk (+ chunk A-sums)
  pool_mfma<<<dim3(64, 2, BATCH), 256, 0, stream>>>(Ab, xb, part, asump);
  // fused reduce + denom + fp32 K/V mini-GEMM
  pool2kv<<<256, 256, 0, stream>>>(part, asump, w_qkv, kcb, vcbT);

  // fused attention: 64 tokens x 4 heads per block; x -> xb (X is dead)
  attn_mfma<<<dim3(NTOK / 64, 2, BATCH), 256, 0, stream>>>(Ab, qb, xb, kcb, vcbT, cbbT);

  // out = x @ w_proj + b_proj (x bf16 in xb, lda 256)
  gemm_mfma<1, 0><<<dim3(2, 512), 256, 0, stream>>>(xb, wpT, b_proj, out,
                                                    256, 256, 256);
}

// Round 9
// 265.584 us; speedup vs baseline: 1.0457x; 1.0226x over previous
//
#include <hip/hip_runtime.h>

#define NTOK 16384
#define BATCH 4

typedef __attribute__((ext_vector_type(8))) short bf16x8;
typedef __attribute__((ext_vector_type(8))) unsigned short ushort8;
typedef __attribute__((ext_vector_type(4))) float f32x4;

__device__ __forceinline__ unsigned short f2bf(float f) {
  union { float f; unsigned int u; } c; c.f = f;
  unsigned int r = c.u + 0x7fff + ((c.u >> 16) & 1);  // RTN-even
  return (unsigned short)(r >> 16);
}

__device__ __forceinline__ float exp2_fast(float x) {
  float r;
  asm("v_exp_f32 %0, %1" : "=v"(r) : "v"(x));
  return r;
}

// fused conversions: blocks <2048 convert voxel+A fp32->bf16 (grid-stride);
// blocks >=2048 transpose+convert weights (cbbT pre-scaled by log2e).
__global__ __launch_bounds__(256) void convall(const float* __restrict__ voxel,
                                               const float* __restrict__ A,
                                               const float* __restrict__ w_qkv,
                                               const float* __restrict__ w_proj,
                                               const float* __restrict__ cb,
                                               unsigned short* __restrict__ xb,
                                               unsigned short* __restrict__ Ab,
                                               unsigned short* __restrict__ wqT,
                                               unsigned short* __restrict__ wpT,
                                               unsigned short* __restrict__ cbbT) {
  const int blk = blockIdx.x;
  const int k = threadIdx.x;
  if (blk < 2048) {
    for (int i = blk * 256 + k; i < 2621440; i += 2048 * 256) {
      const float* src; unsigned short* dst; int j;
      if (i < 2097152) { j = i; src = voxel; dst = xb; }
      else { j = i - 2097152; src = A; dst = Ab; }
      float4 a = *(const float4*)(src + 8 * (size_t)j);
      float4 b = *(const float4*)(src + 8 * (size_t)j + 4);
      ushort8 o;
      o[0] = f2bf(a.x); o[1] = f2bf(a.y); o[2] = f2bf(a.z); o[3] = f2bf(a.w);
      o[4] = f2bf(b.x); o[5] = f2bf(b.y); o[6] = f2bf(b.z); o[7] = f2bf(b.w);
      *(ushort8*)(dst + 8 * (size_t)j) = o;
    }
  } else {
    int n = blk - 2048;
    if (n < 256) wqT[n * 256 + k] = f2bf(w_qkv[(size_t)k * 768 + n]);
    else if (n < 512) wpT[(n - 256) * 256 + k] = f2bf(w_proj[(size_t)k * 256 + (n - 256)]);
    else if (k < 64) {
      for (int j = 0; j < 64; ++j)
        cbbT[k * 64 + j] = f2bf(cb[j * 64 + k] * 1.4426950408889634f);
    }
  }
}

// C[M,N] = A[M,K=256] @ BT[N,K]^T (+bias). MFMA bf16. Tile 128x128, 4 waves.
// K MUST be 256. Single-buffer LDS, 2-deep register prefetch, LDS-staged
// coalesced C writeout.
template <int ADD_BIAS, int C_BF16>
__global__ __launch_bounds__(256, 3) void gemm_mfma(const unsigned short* __restrict__ Ab,
                                                    const unsigned short* __restrict__ BT,
                                                    const float* __restrict__ bias,
                                                    void* __restrict__ Cv,
                                                    int N, int K, int lda) {
  __shared__ __align__(16) unsigned short smem[2][128][72];
  const int tid = threadIdx.x;
  int bx, by;
  if ((gridDim.y & 7) == 0) {
    int flat = blockIdx.y * gridDim.x + blockIdx.x;
    int xc = flat & 7, t = flat >> 3;
    int gx = gridDim.x, ypx = gridDim.y >> 3;
    bx = t % gx; by = xc * ypx + t / gx;
  } else { bx = blockIdx.x; by = blockIdx.y; }
  const int bn = bx * 128, bm = by * 128;
  const int lane = tid & 63;
  const int wv = tid >> 6;
  const int wm = wv & 1, wn = wv >> 1;
  const int m16 = lane & 15, quad = lane >> 4;

  const int srow = tid >> 1;
  const int scol = (tid & 1) * 32;

  const unsigned short* ga = Ab + (size_t)(bm + srow) * lda + scol;
  const unsigned short* gb = BT + (size_t)(bn + srow) * K + scol;

  ushort8 ra[2][4], rb[2][4];
#pragma unroll
  for (int kt = 0; kt < 2; ++kt)
#pragma unroll
    for (int i = 0; i < 4; ++i) {
      ra[kt][i] = *(const ushort8*)(ga + kt * 64 + 8 * i);
      rb[kt][i] = *(const ushort8*)(gb + kt * 64 + 8 * i);
    }

  f32x4 acc[4][4];
#pragma unroll
  for (int r = 0; r < 4; ++r)
#pragma unroll
    for (int c = 0; c < 4; ++c) acc[r][c] = (f32x4){0.f, 0.f, 0.f, 0.f};

#pragma unroll
  for (int kt = 0; kt < 4; ++kt) {
    const int sb = kt & 1;
    if (kt > 0) __syncthreads();
#pragma unroll
    for (int i = 0; i < 4; ++i) {
      *(ushort8*)&smem[0][srow][scol + 8 * i] = ra[sb][i];
      *(ushort8*)&smem[1][srow][scol + 8 * i] = rb[sb][i];
    }
    __syncthreads();
    if (kt < 2) {
#pragma unroll
      for (int i = 0; i < 4; ++i) {
        ra[sb][i] = *(const ushort8*)(ga + (kt + 2) * 64 + 8 * i);
        rb[sb][i] = *(const ushort8*)(gb + (kt + 2) * 64 + 8 * i);
      }
    }
#pragma unroll
    for (int ks = 0; ks < 64; ks += 32) {
      bf16x8 af[4], bf[4];
#pragma unroll
      for (int r = 0; r < 4; ++r)
        af[r] = *(const bf16x8*)&smem[0][wm * 64 + r * 16 + m16][ks + quad * 8];
#pragma unroll
      for (int c = 0; c < 4; ++c)
        bf[c] = *(const bf16x8*)&smem[1][wn * 64 + c * 16 + m16][ks + quad * 8];
#pragma unroll
      for (int r = 0; r < 4; ++r)
#pragma unroll
        for (int c = 0; c < 4; ++c)
          acc[r][c] = __builtin_amdgcn_mfma_f32_16x16x32_bf16(af[r], bf[c], acc[r][c], 0, 0, 0);
    }
  }

  float bv[4];
  if (ADD_BIAS) {
#pragma unroll
    for (int c = 0; c < 4; ++c) bv[c] = bias[bn + wn * 64 + c * 16 + m16];
  }
  const int lrD = tid >> 2, cch = (tid & 3) * 32;
  unsigned short* Csh = (unsigned short*)smem;
  float* Csf = (float*)smem;
#pragma unroll
  for (int p = 0; p < 2; ++p) {
    __syncthreads();
    if (wm == p) {
#pragma unroll
      for (int r = 0; r < 4; ++r) {
        int lr0 = r * 16 + quad * 4;
#pragma unroll
        for (int c = 0; c < 4; ++c) {
          int col = wn * 64 + c * 16 + m16;
#pragma unroll
          for (int i = 0; i < 4; ++i) {
            float v = acc[r][c][i] + (ADD_BIAS ? bv[c] : 0.f);
            if (C_BF16) Csh[(lr0 + i) * 136 + col] = f2bf(v);
            else Csf[(lr0 + i) * 132 + col] = v;
          }
        }
      }
    }
    __syncthreads();
    if (C_BF16) {
      unsigned short* gp = (unsigned short*)Cv + (size_t)(bm + p * 64 + lrD) * N + bn + cch;
      const unsigned short* sp = Csh + lrD * 136 + cch;
      ushort8 t0 = *(const ushort8*)(sp + 0);
      ushort8 t1 = *(const ushort8*)(sp + 8);
      ushort8 t2 = *(const ushort8*)(sp + 16);
      ushort8 t3 = *(const ushort8*)(sp + 24);
      *(ushort8*)(gp + 0) = t0;
      *(ushort8*)(gp + 8) = t1;
      *(ushort8*)(gp + 16) = t2;
      *(ushort8*)(gp + 24) = t3;
    } else {
      float* gp = (float*)Cv + (size_t)(bm + p * 64 + lrD) * N + bn + cch;
      const float* sp = Csf + lrD * 132 + cch;
      float4 t[8];
#pragma unroll
      for (int u = 0; u < 8; ++u) t[u] = *(const float4*)(sp + 4 * u);
#pragma unroll
      for (int u = 0; u < 8; ++u) *(float4*)(gp + 4 * u) = t[u];
    }
  }
}

// ---- pool X via MFMA: part[b][tch][cl 64][ch 256] over 256-token chunks.
// cblk==0 blocks also compute chunk A-sums (A^T @ ones) -> asump[b][tch][cl].
__global__ __launch_bounds__(256) void pool_mfma(const unsigned short* __restrict__ Ab,
                                                 const unsigned short* __restrict__ xb,
                                                 float* __restrict__ part,
                                                 float* __restrict__ asump) {
  __shared__ unsigned short At[64][40];
  __shared__ unsigned short Xt[128][40];
  const int tid = threadIdx.x;
  const int tch = blockIdx.x, cblk = blockIdx.y, b = blockIdx.z;
  const int w = tid >> 6, lane = tid & 63;
  const int m16 = lane & 15, quad = lane >> 4;
  const size_t row0 = (size_t)b * NTOK + (size_t)tch * 256;
  const int cb0 = cblk * 128;
  const int tokL = tid & 31, gA = tid >> 5;

  f32x4 acc[4][2];
#pragma unroll
  for (int r = 0; r < 4; ++r)
#pragma unroll
    for (int c = 0; c < 2; ++c) acc[r][c] = (f32x4){0.f, 0.f, 0.f, 0.f};
  f32x4 acc1[4];
#pragma unroll
  for (int r = 0; r < 4; ++r) acc1[r] = (f32x4){0.f, 0.f, 0.f, 0.f};
  bf16x8 onesv;
#pragma unroll
  for (int i = 0; i < 8; ++i) onesv[i] = (short)0x3F80;  // bf16 1.0

  ushort8 px[2], pa;
  auto loadG = [&](int t0) {
#pragma unroll
    for (int u = 0; u < 2; ++u) {
      int idx = tid + u * 256;
      int tok = idx & 31, g = idx >> 5;
      px[u] = *(const ushort8*)(xb + (row0 + t0 + tok) * 256 + cb0 + g * 8);
    }
    pa = *(const ushort8*)(Ab + (row0 + t0 + tokL) * 64 + gA * 8);
  };
  loadG(0);

  for (int ks = 0; ks < 8; ++ks) {
    __syncthreads();
#pragma unroll
    for (int u = 0; u < 2; ++u) {
      int idx = tid + u * 256;
      int tok = idx & 31, g = idx >> 5;
#pragma unroll
      for (int i = 0; i < 8; ++i) Xt[g * 8 + i][tok] = (unsigned short)px[u][i];
    }
#pragma unroll
    for (int i = 0; i < 8; ++i) At[gA * 8 + i][tokL] = (unsigned short)pa[i];
    __syncthreads();
    if (ks + 1 < 8) loadG((ks + 1) * 32);
    bf16x8 af[4], bfr[2];
#pragma unroll
    for (int r = 0; r < 4; ++r) af[r] = *(const bf16x8*)&At[r * 16 + m16][quad * 8];
#pragma unroll
    for (int c = 0; c < 2; ++c) bfr[c] = *(const bf16x8*)&Xt[w * 32 + c * 16 + m16][quad * 8];
#pragma unroll
    for (int r = 0; r < 4; ++r)
#pragma unroll
      for (int c = 0; c < 2; ++c)
        acc[r][c] = __builtin_amdgcn_mfma_f32_16x16x32_bf16(af[r], bfr[c], acc[r][c], 0, 0, 0);
    if (cblk == 0) {
#pragma unroll
      for (int r = 0; r < 4; ++r)
        acc1[r] = __builtin_amdgcn_mfma_f32_16x16x32_bf16(af[r], onesv, acc1[r], 0, 0, 0);
    }
  }

  float* pp = part + ((size_t)(b * 64 + tch) * 64) * 256 + cb0;
#pragma unroll
  for (int r = 0; r < 4; ++r)
#pragma unroll
    for (int c = 0; c < 2; ++c)
#pragma unroll
      for (int i = 0; i < 4; ++i) {
        int cl = r * 16 + quad * 4 + i;
        int ch = w * 32 + c * 16 + m16;
        pp[(size_t)cl * 256 + ch] = acc[r][c][i];
      }
  if (cblk == 0 && tid < 64 && m16 == 0) {
    float* ap = asump + ((size_t)(b * 64 + tch)) * 64;
#pragma unroll
    for (int r = 0; r < 4; ++r)
#pragma unroll
      for (int i = 0; i < 4; ++i)
        ap[r * 16 + quad * 4 + i] = acc1[r][i];
  }
}

// fused: reduce 64 chunks of part -> pooledX row (f32), wave-reduce asump ->
// denom, then fp32 K/V mini-GEMM vs w_qkv[:,256:768]. One block per (b,cl).
__global__ __launch_bounds__(256) void pool2kv(const float* __restrict__ part,
                                               const float* __restrict__ asump,
                                               const float* __restrict__ w_qkv,
                                               unsigned short* __restrict__ kcb,
                                               unsigned short* __restrict__ vcbT) {
  __shared__ float px[256];
  __shared__ float dsh;
  const int bc = blockIdx.x;  // b*64 + cl
  const int b = bc >> 6, cl = bc & 63;
  const int c = threadIdx.x;
  if (c < 64) {
    float av = asump[((size_t)(b * 64) + c) * 64 + cl];
#pragma unroll
    for (int msk = 1; msk < 64; msk <<= 1) av += __shfl_xor(av, msk);
    if (c == 0) dsh = av + 1e-8f;
  }
  const float* pp = part + ((size_t)(b * 64) * 64 + cl) * 256 + c;
  float s = 0.f;
#pragma unroll 4
  for (int t = 0; t < 64; ++t) s += pp[(size_t)t * 16384];
  px[c] = s;
  __syncthreads();
  float accK = 0.f, accV = 0.f;
#pragma unroll 8
  for (int k = 0; k < 256; ++k) {
    float x = px[k];
    accK = fmaf(x, w_qkv[(size_t)k * 768 + 256 + c], accK);
    accV = fmaf(x, w_qkv[(size_t)k * 768 + 512 + c], accV);
  }
  float inv = 1.f / dsh;
  int h = c >> 5, d = c & 31;
  kcb[(((size_t)b * 8 + h) * 64 + cl) * 32 + d] =
      f2bf(accK * inv * (0.17677669529663687f * 1.4426950408889634f));
  vcbT[(((size_t)b * 8 + h) * 32 + d) * 64 + cl] = f2bf(accV * inv);
}

// ---- fused attention v5: 64 tokens x 4 heads per block. ALL fragment loads
// (A, cbbT, 4x Q/KC/VT) issued upfront into registers -> ONE HBM latency
// exposure per block (v4's 48-VGPR compile serialized per-head loads).
// __launch_bounds__(256,2) grants the register budget (~200 VGPR of frags).
// Head loop is pure register/LDS compute. Zero barriers. exp2 softmax. ----
__global__ __launch_bounds__(256, 2) void attn_mfma(const unsigned short* __restrict__ Ab,
                                                    const unsigned short* __restrict__ qb,
                                                    unsigned short* __restrict__ xout,
                                                    const unsigned short* __restrict__ kcb,
                                                    const unsigned short* __restrict__ vcbT,
                                                    const unsigned short* __restrict__ cbbT) {
  __shared__ __align__(16) unsigned short PA[64 * 72];  // P tile
  __shared__ __align__(16) unsigned short XO[64 * 36];  // x staging

  const int tid = threadIdx.x;
  const int nb = blockIdx.x, hq = blockIdx.y, b = blockIdx.z;
  const int h0 = hq * 4;
  const int w = tid >> 6, lane = tid & 63;
  const int m16 = lane & 15, quad = lane >> 4;
  const size_t row0 = (size_t)b * NTOK + (size_t)nb * 64;
  const int rA = w * 16 + m16;
  const size_t bh8 = (size_t)b * 8;
  const int l4 = lane >> 2, s3 = lane & 3;

  // ---- ALL loads upfront: single latency exposure ----
  bf16x8 aA[2], cbf[2][4];
  bf16x8 qf[4], kcf[4][4], vtf[4][2][2];
#pragma unroll
  for (int ks = 0; ks < 2; ++ks)
    aA[ks] = *(const bf16x8*)(Ab + (row0 + rA) * 64 + ks * 32 + quad * 8);
#pragma unroll
  for (int hh = 0; hh < 4; ++hh)
    qf[hh] = *(const bf16x8*)(qb + (row0 + rA) * 256 + (h0 + hh) * 32 + quad * 8);
#pragma unroll
  for (int hh = 0; hh < 4; ++hh)
#pragma unroll
    for (int nt = 0; nt < 4; ++nt)
      kcf[hh][nt] = *(const bf16x8*)(kcb + ((bh8 + h0 + hh) * 64 + nt * 16 + m16) * 32 +
                                     quad * 8);
#pragma unroll
  for (int hh = 0; hh < 4; ++hh)
#pragma unroll
    for (int nt2 = 0; nt2 < 2; ++nt2)
#pragma unroll
      for (int kc2 = 0; kc2 < 2; ++kc2)
        vtf[hh][nt2][kc2] = *(const bf16x8*)(vcbT + ((bh8 + h0 + hh) * 32 + nt2 * 16 + m16) * 64 +
                                             kc2 * 32 + quad * 8);
#pragma unroll
  for (int ks = 0; ks < 2; ++ks)
#pragma unroll
    for (int nt = 0; nt < 4; ++nt)
      cbf[ks][nt] = *(const bf16x8*)(cbbT + (nt * 16 + m16) * 64 + ks * 32 + quad * 8);

  // ---- bias = A @ cbT (K=64); consumes aA/cbf first (frees regs) ----
  f32x4 bacc[4];
#pragma unroll
  for (int nt = 0; nt < 4; ++nt) bacc[nt] = (f32x4){0.f, 0.f, 0.f, 0.f};
#pragma unroll
  for (int ks = 0; ks < 2; ++ks)
#pragma unroll
    for (int nt = 0; nt < 4; ++nt)
      bacc[nt] = __builtin_amdgcn_mfma_f32_16x16x32_bf16(aA[ks], cbf[ks][nt], bacc[nt], 0, 0, 0);

#pragma unroll
  for (int hh = 0; hh < 4; ++hh) {
    const int h = h0 + hh;

    // scores (log2 domain) = bias + q @ kc^T
    f32x4 acc[4];
#pragma unroll
    for (int nt = 0; nt < 4; ++nt)
      acc[nt] = __builtin_amdgcn_mfma_f32_16x16x32_bf16(qf[hh], kcf[hh][nt], bacc[nt], 0, 0, 0);

    // softmax: row = quad*4+i, 64 cols = nt x m16
    f32x4 mxv, sv;
#pragma unroll
    for (int i = 0; i < 4; ++i)
      mxv[i] = fmaxf(fmaxf(acc[0][i], acc[1][i]), fmaxf(acc[2][i], acc[3][i]));
#pragma unroll
    for (int msk = 1; msk < 16; msk <<= 1)
#pragma unroll
      for (int i = 0; i < 4; ++i) mxv[i] = fmaxf(mxv[i], __shfl_xor(mxv[i], msk));
#pragma unroll
    for (int i = 0; i < 4; ++i) sv[i] = 0.f;
#pragma unroll
    for (int nt = 0; nt < 4; ++nt)
#pragma unroll
      for (int i = 0; i < 4; ++i) {
        float e = exp2_fast(acc[nt][i] - mxv[i]);
        acc[nt][i] = e;
        sv[i] += e;
      }
    // P (unnormalized) -> LDS immediately; sum-reduce overlaps
#pragma unroll
    for (int nt = 0; nt < 4; ++nt)
#pragma unroll
      for (int i = 0; i < 4; ++i)
        PA[(w * 16 + quad * 4 + i) * 72 + nt * 16 + m16] = f2bf(acc[nt][i]);
#pragma unroll
    for (int msk = 1; msk < 16; msk <<= 1)
#pragma unroll
      for (int i = 0; i < 4; ++i) sv[i] += __shfl_xor(sv[i], msk);
#pragma unroll
    for (int i = 0; i < 4; ++i) sv[i] = 1.f / sv[i];

    // x = (P @ vcT) * (1/l)
    f32x4 acc2[2];
#pragma unroll
    for (int nt2 = 0; nt2 < 2; ++nt2) acc2[nt2] = (f32x4){0.f, 0.f, 0.f, 0.f};
#pragma unroll
    for (int kc2 = 0; kc2 < 2; ++kc2) {
      bf16x8 pf = *(const bf16x8*)&PA[rA * 72 + kc2 * 32 + quad * 8];
#pragma unroll
      for (int nt2 = 0; nt2 < 2; ++nt2)
        acc2[nt2] = __builtin_amdgcn_mfma_f32_16x16x32_bf16(pf, vtf[hh][nt2][kc2], acc2[nt2], 0, 0, 0);
    }

    // stage x in wave-local LDS, then coalesced 16B stores
#pragma unroll
    for (int nt2 = 0; nt2 < 2; ++nt2)
#pragma unroll
      for (int i = 0; i < 4; ++i)
        XO[(w * 16 + quad * 4 + i) * 36 + nt2 * 16 + m16] = f2bf(acc2[nt2][i] * sv[i]);
    ushort8 xv = *(const ushort8*)&XO[(w * 16 + l4) * 36 + s3 * 8];
    *(ushort8*)(xout + (row0 + w * 16 + l4) * 256 + h * 32 + s3 * 8) = xv;
  }
}

extern "C" void kernel_launch(void* const* d_in, const int* in_sizes, int n_in,
                              void* d_out, int out_size, void* d_ws, size_t ws_size,
                              hipStream_t stream) {
  const float* voxel  = (const float*)d_in[0];
  const float* A      = (const float*)d_in[1];
  const float* w_qkv  = (const float*)d_in[2];
  const float* w_proj = (const float*)d_in[3];
  const float* b_proj = (const float*)d_in[4];
  const float* cb     = (const float*)d_in[5];
  float* out = (float*)d_out;
  (void)in_sizes; (void)n_in; (void)out_size; (void)ws_size;

  // ws layout (byte offsets / sizes):
  // qb      0         33554432
  // xb      33554432  33554432   (X bf16; overwritten with x by attn)
  // part    67108864  16777216
  // asump   83886080  65536
  // wqT     83951616  131072
  // wpT     84082688  131072
  // kcb     84213760  131072
  // vcbT    84344832  131072
  // cbbT    84475904  8192
  char* wsb = (char*)d_ws;
  unsigned short* qb       = (unsigned short*)wsb;
  unsigned short* xb       = (unsigned short*)(wsb + 33554432);
  float* part              = (float*)(wsb + 67108864);
  float* asump             = (float*)(wsb + 83886080);
  unsigned short* wqT      = (unsigned short*)(wsb + 83951616);
  unsigned short* wpT      = (unsigned short*)(wsb + 84082688);
  unsigned short* kcb      = (unsigned short*)(wsb + 84213760);
  unsigned short* vcbT     = (unsigned short*)(wsb + 84344832);
  unsigned short* cbbT     = (unsigned short*)(wsb + 84475904);
  // Ab (bf16 A, 8 MB) parked in d_out: dead before the final GEMM writes out
  unsigned short* Ab = (unsigned short*)d_out;

  // fused conversions (voxel/A bf16 + weight transposes)
  convall<<<2561, 256, 0, stream>>>(voxel, A, w_qkv, w_proj, cb,
                                    xb, Ab, wqT, wpT, cbbT);

  // Q only: qb(bf16) = xb @ Wq
  gemm_mfma<0, 1><<<dim3(2, 512), 256, 0, stream>>>(xb, wqT, nullptr, qb,
                                                    256, 256, 256);

  // pooledX partials = A^T @ X per 256-token chunk (+ chunk A-sums)
  pool_mfma<<<dim3(64, 2, BATCH), 256, 0, stream>>>(Ab, xb, part, asump);
  // fused reduce + denom + fp32 K/V mini-GEMM
  pool2kv<<<256, 256, 0, stream>>>(part, asump, w_qkv, kcb, vcbT);

  // fused attention: 64 tokens x 4 heads per block; x -> xb (X is dead)
  attn_mfma<<<dim3(NTOK / 64, 2, BATCH), 256, 0, stream>>>(Ab, qb, xb, kcb, vcbT, cbbT);

  // out = x @ w_proj + b_proj (x bf16 in xb, lda 256)
  gemm_mfma<1, 0><<<dim3(2, 512), 256, 0, stream>>>(xb, wpT, b_proj, out,
                                                    256, 256, 256);
}

// Round 10
// 254.764 us; speedup vs baseline: 1.0901x; 1.0425x over previous
//
#include <hip/hip_runtime.h>

#define NTOK 16384
#define BATCH 4

typedef __attribute__((ext_vector_type(8))) short bf16x8;
typedef __attribute__((ext_vector_type(8))) unsigned short ushort8;
typedef __attribute__((ext_vector_type(4))) float f32x4;

__device__ __forceinline__ unsigned short f2bf(float f) {
  union { float f; unsigned int u; } c; c.f = f;
  unsigned int r = c.u + 0x7fff + ((c.u >> 16) & 1);  // RTN-even
  return (unsigned short)(r >> 16);
}

__device__ __forceinline__ float exp2_fast(float x) {
  float r;
  asm("v_exp_f32 %0, %1" : "=v"(r) : "v"(x));
  return r;
}

// fused conversions: blocks <2048 convert voxel+A fp32->bf16 (grid-stride);
// blocks >=2048 transpose+convert weights (cbbT pre-scaled by log2e).
__global__ __launch_bounds__(256) void convall(const float* __restrict__ voxel,
                                               const float* __restrict__ A,
                                               const float* __restrict__ w_qkv,
                                               const float* __restrict__ w_proj,
                                               const float* __restrict__ cb,
                                               unsigned short* __restrict__ xb,
                                               unsigned short* __restrict__ Ab,
                                               unsigned short* __restrict__ wqT,
                                               unsigned short* __restrict__ wpT,
                                               unsigned short* __restrict__ cbbT) {
  const int blk = blockIdx.x;
  const int k = threadIdx.x;
  if (blk < 2048) {
    for (int i = blk * 256 + k; i < 2621440; i += 2048 * 256) {
      const float* src; unsigned short* dst; int j;
      if (i < 2097152) { j = i; src = voxel; dst = xb; }
      else { j = i - 2097152; src = A; dst = Ab; }
      float4 a = *(const float4*)(src + 8 * (size_t)j);
      float4 b = *(const float4*)(src + 8 * (size_t)j + 4);
      ushort8 o;
      o[0] = f2bf(a.x); o[1] = f2bf(a.y); o[2] = f2bf(a.z); o[3] = f2bf(a.w);
      o[4] = f2bf(b.x); o[5] = f2bf(b.y); o[6] = f2bf(b.z); o[7] = f2bf(b.w);
      *(ushort8*)(dst + 8 * (size_t)j) = o;
    }
  } else {
    int n = blk - 2048;
    if (n < 256) wqT[n * 256 + k] = f2bf(w_qkv[(size_t)k * 768 + n]);
    else if (n < 512) wpT[(n - 256) * 256 + k] = f2bf(w_proj[(size_t)k * 256 + (n - 256)]);
    else if (k < 64) {
      for (int j = 0; j < 64; ++j)
        cbbT[k * 64 + j] = f2bf(cb[j * 64 + k] * 1.4426950408889634f);
    }
  }
}

// C[M,N] = A[M,K=256] @ BT[N,K]^T (+bias), f32 out. MFMA bf16. Tile 128x128.
// Used for the final projection only.
__global__ __launch_bounds__(256, 3) void gemm_proj(const unsigned short* __restrict__ Ab,
                                                    const unsigned short* __restrict__ BT,
                                                    const float* __restrict__ bias,
                                                    float* __restrict__ Cv,
                                                    int N, int K, int lda) {
  __shared__ __align__(16) unsigned short smem[2][128][72];
  const int tid = threadIdx.x;
  int bx, by;
  if ((gridDim.y & 7) == 0) {
    int flat = blockIdx.y * gridDim.x + blockIdx.x;
    int xc = flat & 7, t = flat >> 3;
    int gx = gridDim.x, ypx = gridDim.y >> 3;
    bx = t % gx; by = xc * ypx + t / gx;
  } else { bx = blockIdx.x; by = blockIdx.y; }
  const int bn = bx * 128, bm = by * 128;
  const int lane = tid & 63;
  const int wv = tid >> 6;
  const int wm = wv & 1, wn = wv >> 1;
  const int m16 = lane & 15, quad = lane >> 4;

  const int srow = tid >> 1;
  const int scol = (tid & 1) * 32;

  const unsigned short* ga = Ab + (size_t)(bm + srow) * lda + scol;
  const unsigned short* gb = BT + (size_t)(bn + srow) * K + scol;

  ushort8 ra[2][4], rb[2][4];
#pragma unroll
  for (int kt = 0; kt < 2; ++kt)
#pragma unroll
    for (int i = 0; i < 4; ++i) {
      ra[kt][i] = *(const ushort8*)(ga + kt * 64 + 8 * i);
      rb[kt][i] = *(const ushort8*)(gb + kt * 64 + 8 * i);
    }

  f32x4 acc[4][4];
#pragma unroll
  for (int r = 0; r < 4; ++r)
#pragma unroll
    for (int c = 0; c < 4; ++c) acc[r][c] = (f32x4){0.f, 0.f, 0.f, 0.f};

#pragma unroll
  for (int kt = 0; kt < 4; ++kt) {
    const int sb = kt & 1;
    if (kt > 0) __syncthreads();
#pragma unroll
    for (int i = 0; i < 4; ++i) {
      *(ushort8*)&smem[0][srow][scol + 8 * i] = ra[sb][i];
      *(ushort8*)&smem[1][srow][scol + 8 * i] = rb[sb][i];
    }
    __syncthreads();
    if (kt < 2) {
#pragma unroll
      for (int i = 0; i < 4; ++i) {
        ra[sb][i] = *(const ushort8*)(ga + (kt + 2) * 64 + 8 * i);
        rb[sb][i] = *(const ushort8*)(gb + (kt + 2) * 64 + 8 * i);
      }
    }
#pragma unroll
    for (int ks = 0; ks < 64; ks += 32) {
      bf16x8 af[4], bf[4];
#pragma unroll
      for (int r = 0; r < 4; ++r)
        af[r] = *(const bf16x8*)&smem[0][wm * 64 + r * 16 + m16][ks + quad * 8];
#pragma unroll
      for (int c = 0; c < 4; ++c)
        bf[c] = *(const bf16x8*)&smem[1][wn * 64 + c * 16 + m16][ks + quad * 8];
#pragma unroll
      for (int r = 0; r < 4; ++r)
#pragma unroll
        for (int c = 0; c < 4; ++c)
          acc[r][c] = __builtin_amdgcn_mfma_f32_16x16x32_bf16(af[r], bf[c], acc[r][c], 0, 0, 0);
    }
  }

  float bv[4];
#pragma unroll
  for (int c = 0; c < 4; ++c) bv[c] = bias[bn + wn * 64 + c * 16 + m16];
  const int lrD = tid >> 2, cch = (tid & 3) * 32;
  float* Csf = (float*)smem;
#pragma unroll
  for (int p = 0; p < 2; ++p) {
    __syncthreads();
    if (wm == p) {
#pragma unroll
      for (int r = 0; r < 4; ++r) {
        int lr0 = r * 16 + quad * 4;
#pragma unroll
        for (int c = 0; c < 4; ++c) {
          int col = wn * 64 + c * 16 + m16;
#pragma unroll
          for (int i = 0; i < 4; ++i)
            Csf[(lr0 + i) * 132 + col] = acc[r][c][i] + bv[c];
        }
      }
    }
    __syncthreads();
    float* gp = Cv + (size_t)(bm + p * 64 + lrD) * N + bn + cch;
    const float* sp = Csf + lrD * 132 + cch;
    float4 t[8];
#pragma unroll
    for (int u = 0; u < 8; ++u) t[u] = *(const float4*)(sp + 4 * u);
#pragma unroll
    for (int u = 0; u < 8; ++u) *(float4*)(gp + 4 * u) = t[u];
  }
}

// ---- pool X via MFMA: part[b][tch][cl 64][ch 256] over 256-token chunks.
// cblk==0 blocks also compute chunk A-sums (A^T @ ones) -> asump[b][tch][cl].
__global__ __launch_bounds__(256) void pool_mfma(const unsigned short* __restrict__ Ab,
                                                 const unsigned short* __restrict__ xb,
                                                 float* __restrict__ part,
                                                 float* __restrict__ asump) {
  __shared__ unsigned short At[64][40];
  __shared__ unsigned short Xt[128][40];
  const int tid = threadIdx.x;
  const int tch = blockIdx.x, cblk = blockIdx.y, b = blockIdx.z;
  const int w = tid >> 6, lane = tid & 63;
  const int m16 = lane & 15, quad = lane >> 4;
  const size_t row0 = (size_t)b * NTOK + (size_t)tch * 256;
  const int cb0 = cblk * 128;
  const int tokL = tid & 31, gA = tid >> 5;

  f32x4 acc[4][2];
#pragma unroll
  for (int r = 0; r < 4; ++r)
#pragma unroll
    for (int c = 0; c < 2; ++c) acc[r][c] = (f32x4){0.f, 0.f, 0.f, 0.f};
  f32x4 acc1[4];
#pragma unroll
  for (int r = 0; r < 4; ++r) acc1[r] = (f32x4){0.f, 0.f, 0.f, 0.f};
  bf16x8 onesv;
#pragma unroll
  for (int i = 0; i < 8; ++i) onesv[i] = (short)0x3F80;  // bf16 1.0

  ushort8 px[2], pa;
  auto loadG = [&](int t0) {
#pragma unroll
    for (int u = 0; u < 2; ++u) {
      int idx = tid + u * 256;
      int tok = idx & 31, g = idx >> 5;
      px[u] = *(const ushort8*)(xb + (row0 + t0 + tok) * 256 + cb0 + g * 8);
    }
    pa = *(const ushort8*)(Ab + (row0 + t0 + tokL) * 64 + gA * 8);
  };
  loadG(0);

  for (int ks = 0; ks < 8; ++ks) {
    __syncthreads();
#pragma unroll
    for (int u = 0; u < 2; ++u) {
      int idx = tid + u * 256;
      int tok = idx & 31, g = idx >> 5;
#pragma unroll
      for (int i = 0; i < 8; ++i) Xt[g * 8 + i][tok] = (unsigned short)px[u][i];
    }
#pragma unroll
    for (int i = 0; i < 8; ++i) At[gA * 8 + i][tokL] = (unsigned short)pa[i];
    __syncthreads();
    if (ks + 1 < 8) loadG((ks + 1) * 32);
    bf16x8 af[4], bfr[2];
#pragma unroll
    for (int r = 0; r < 4; ++r) af[r] = *(const bf16x8*)&At[r * 16 + m16][quad * 8];
#pragma unroll
    for (int c = 0; c < 2; ++c) bfr[c] = *(const bf16x8*)&Xt[w * 32 + c * 16 + m16][quad * 8];
#pragma unroll
    for (int r = 0; r < 4; ++r)
#pragma unroll
      for (int c = 0; c < 2; ++c)
        acc[r][c] = __builtin_amdgcn_mfma_f32_16x16x32_bf16(af[r], bfr[c], acc[r][c], 0, 0, 0);
    if (cblk == 0) {
#pragma unroll
      for (int r = 0; r < 4; ++r)
        acc1[r] = __builtin_amdgcn_mfma_f32_16x16x32_bf16(af[r], onesv, acc1[r], 0, 0, 0);
    }
  }

  float* pp = part + ((size_t)(b * 64 + tch) * 64) * 256 + cb0;
#pragma unroll
  for (int r = 0; r < 4; ++r)
#pragma unroll
    for (int c = 0; c < 2; ++c)
#pragma unroll
      for (int i = 0; i < 4; ++i) {
        int cl = r * 16 + quad * 4 + i;
        int ch = w * 32 + c * 16 + m16;
        pp[(size_t)cl * 256 + ch] = acc[r][c][i];
      }
  if (cblk == 0 && tid < 64 && m16 == 0) {
    float* ap = asump + ((size_t)(b * 64 + tch)) * 64;
#pragma unroll
    for (int r = 0; r < 4; ++r)
#pragma unroll
      for (int i = 0; i < 4; ++i)
        ap[r * 16 + quad * 4 + i] = acc1[r][i];
  }
}

// fused: reduce 64 chunks of part -> pooledX row (f32), wave-reduce asump ->
// denom, then fp32 K/V mini-GEMM vs w_qkv[:,256:768]. One block per (b,cl).
__global__ __launch_bounds__(256) void pool2kv(const float* __restrict__ part,
                                               const float* __restrict__ asump,
                                               const float* __restrict__ w_qkv,
                                               unsigned short* __restrict__ kcb,
                                               unsigned short* __restrict__ vcbT) {
  __shared__ float px[256];
  __shared__ float dsh;
  const int bc = blockIdx.x;  // b*64 + cl
  const int b = bc >> 6, cl = bc & 63;
  const int c = threadIdx.x;
  if (c < 64) {
    float av = asump[((size_t)(b * 64) + c) * 64 + cl];
#pragma unroll
    for (int msk = 1; msk < 64; msk <<= 1) av += __shfl_xor(av, msk);
    if (c == 0) dsh = av + 1e-8f;
  }
  const float* pp = part + ((size_t)(b * 64) * 64 + cl) * 256 + c;
  float s = 0.f;
#pragma unroll 4
  for (int t = 0; t < 64; ++t) s += pp[(size_t)t * 16384];
  px[c] = s;
  __syncthreads();
  float accK = 0.f, accV = 0.f;
#pragma unroll 8
  for (int k = 0; k < 256; ++k) {
    float x = px[k];
    accK = fmaf(x, w_qkv[(size_t)k * 768 + 256 + c], accK);
    accV = fmaf(x, w_qkv[(size_t)k * 768 + 512 + c], accV);
  }
  float inv = 1.f / dsh;
  int h = c >> 5, d = c & 31;
  kcb[(((size_t)b * 8 + h) * 64 + cl) * 32 + d] =
      f2bf(accK * inv * (0.17677669529663687f * 1.4426950408889634f));
  vcbT[(((size_t)b * 8 + h) * 32 + d) * 64 + cl] = f2bf(accV * inv);
}

// ---- FUSED Q-GEMM + attention: block = 128 tokens x 128 cols (= 4 heads).
// GEMM phase (identical math to the old Q-GEMM + bf16 round) keeps Q in LDS,
// then each wave runs attention on its 32 tokens x 4 heads (Q from LDS,
// K/V/cb from L2), x -> xout (the old qb buffer). Deletes the standalone attn
// kernel, its 32MB qb write + 32MB read, and one launch. ----
__global__ __launch_bounds__(256, 3) void qattn(const unsigned short* __restrict__ xb,
                                                const unsigned short* __restrict__ wqT,
                                                const unsigned short* __restrict__ Ab,
                                                const unsigned short* __restrict__ kcb,
                                                const unsigned short* __restrict__ vcbT,
                                                const unsigned short* __restrict__ cbbT,
                                                unsigned short* __restrict__ xout) {
  __shared__ __align__(16) unsigned short smem[2][128][72];  // staging; Qs overlays
  __shared__ __align__(16) unsigned short Ps[128 * 68];      // P / x staging
  unsigned short* Qs = (unsigned short*)smem;                // [128][132] (33792 B)

  const int tid = threadIdx.x;
  int bx, by;
  {
    int flat = blockIdx.y * gridDim.x + blockIdx.x;
    int xc = flat & 7, t = flat >> 3;
    int gx = gridDim.x, ypx = gridDim.y >> 3;
    bx = t % gx; by = xc * ypx + t / gx;
  }
  const int bn = bx * 128, bm = by * 128;
  const int lane = tid & 63;
  const int wv = tid >> 6;
  const int wm = wv & 1, wn = wv >> 1;
  const int m16 = lane & 15, quad = lane >> 4;
  const int srow = tid >> 1;
  const int scol = (tid & 1) * 32;

  // ================= GEMM phase: Q = X @ WqT (cols bn..bn+128) ==============
  const unsigned short* ga = xb + (size_t)(bm + srow) * 256 + scol;
  const unsigned short* gb = wqT + (size_t)(bn + srow) * 256 + scol;

  ushort8 ra[2][4], rb[2][4];
#pragma unroll
  for (int kt = 0; kt < 2; ++kt)
#pragma unroll
    for (int i = 0; i < 4; ++i) {
      ra[kt][i] = *(const ushort8*)(ga + kt * 64 + 8 * i);
      rb[kt][i] = *(const ushort8*)(gb + kt * 64 + 8 * i);
    }

  f32x4 acc[4][4];
#pragma unroll
  for (int r = 0; r < 4; ++r)
#pragma unroll
    for (int c = 0; c < 4; ++c) acc[r][c] = (f32x4){0.f, 0.f, 0.f, 0.f};

#pragma unroll
  for (int kt = 0; kt < 4; ++kt) {
    const int sb = kt & 1;
    if (kt > 0) __syncthreads();
#pragma unroll
    for (int i = 0; i < 4; ++i) {
      *(ushort8*)&smem[0][srow][scol + 8 * i] = ra[sb][i];
      *(ushort8*)&smem[1][srow][scol + 8 * i] = rb[sb][i];
    }
    __syncthreads();
    if (kt < 2) {
#pragma unroll
      for (int i = 0; i < 4; ++i) {
        ra[sb][i] = *(const ushort8*)(ga + (kt + 2) * 64 + 8 * i);
        rb[sb][i] = *(const ushort8*)(gb + (kt + 2) * 64 + 8 * i);
      }
    }
#pragma unroll
    for (int ks = 0; ks < 64; ks += 32) {
      bf16x8 af[4], bf[4];
#pragma unroll
      for (int r = 0; r < 4; ++r)
        af[r] = *(const bf16x8*)&smem[0][wm * 64 + r * 16 + m16][ks + quad * 8];
#pragma unroll
      for (int c = 0; c < 4; ++c)
        bf[c] = *(const bf16x8*)&smem[1][wn * 64 + c * 16 + m16][ks + quad * 8];
#pragma unroll
      for (int r = 0; r < 4; ++r)
#pragma unroll
        for (int c = 0; c < 4; ++c)
          acc[r][c] = __builtin_amdgcn_mfma_f32_16x16x32_bf16(af[r], bf[c], acc[r][c], 0, 0, 0);
    }
  }

  // Q tile -> LDS bf16 (same rounding as the old qb roundtrip)
  __syncthreads();
#pragma unroll
  for (int r = 0; r < 4; ++r) {
    int lr0 = wm * 64 + r * 16 + quad * 4;
#pragma unroll
    for (int c = 0; c < 4; ++c) {
      int col = wn * 64 + c * 16 + m16;
#pragma unroll
      for (int i = 0; i < 4; ++i)
        Qs[(lr0 + i) * 132 + col] = f2bf(acc[r][c][i]);
    }
  }
  __syncthreads();

  // ================= attention phase: wave w owns tokens w*32..w*32+32 ======
  const int w = wv;
  const int b = bm >> 14;               // batch (tile never crosses batch)
  const size_t bh8 = (size_t)b * 8;
  const int h0 = bx * 4;
  const int tr0 = w * 32;

  // bias = A @ cbT (K=64, log2-domain table)
  f32x4 bacc[2][4];
#pragma unroll
  for (int rt = 0; rt < 2; ++rt)
#pragma unroll
    for (int nt = 0; nt < 4; ++nt) bacc[rt][nt] = (f32x4){0.f, 0.f, 0.f, 0.f};
#pragma unroll
  for (int ks = 0; ks < 2; ++ks) {
    bf16x8 aA[2], cbf[4];
#pragma unroll
    for (int rt = 0; rt < 2; ++rt)
      aA[rt] = *(const bf16x8*)(Ab + (size_t)(bm + tr0 + rt * 16 + m16) * 64 +
                                ks * 32 + quad * 8);
#pragma unroll
    for (int nt = 0; nt < 4; ++nt)
      cbf[nt] = *(const bf16x8*)(cbbT + (nt * 16 + m16) * 64 + ks * 32 + quad * 8);
#pragma unroll
    for (int rt = 0; rt < 2; ++rt)
#pragma unroll
      for (int nt = 0; nt < 4; ++nt)
        bacc[rt][nt] = __builtin_amdgcn_mfma_f32_16x16x32_bf16(aA[rt], cbf[nt], bacc[rt][nt], 0, 0, 0);
  }

#pragma unroll
  for (int hh = 0; hh < 4; ++hh) {
    const int h = h0 + hh;

    // fragments: Q from LDS, KC/VT from global (L2-hot)
    bf16x8 qf[2];
#pragma unroll
    for (int rt = 0; rt < 2; ++rt)
      qf[rt] = *(const bf16x8*)&Qs[(tr0 + rt * 16 + m16) * 132 + hh * 32 + quad * 8];
    bf16x8 kcf[4];
#pragma unroll
    for (int nt = 0; nt < 4; ++nt)
      kcf[nt] = *(const bf16x8*)(kcb + ((bh8 + h) * 64 + nt * 16 + m16) * 32 + quad * 8);
    bf16x8 vtf[2][2];
#pragma unroll
    for (int nt2 = 0; nt2 < 2; ++nt2)
#pragma unroll
      for (int kc2 = 0; kc2 < 2; ++kc2)
        vtf[nt2][kc2] = *(const bf16x8*)(vcbT + ((bh8 + h) * 32 + nt2 * 16 + m16) * 64 +
                                         kc2 * 32 + quad * 8);

    // scores (log2 domain) = bias + q @ kc^T
    f32x4 sacc[2][4];
#pragma unroll
    for (int rt = 0; rt < 2; ++rt)
#pragma unroll
      for (int nt = 0; nt < 4; ++nt)
        sacc[rt][nt] = __builtin_amdgcn_mfma_f32_16x16x32_bf16(qf[rt], kcf[nt], bacc[rt][nt], 0, 0, 0);

    // softmax per rt: row = tr0 + rt*16 + quad*4 + i, 64 cols = nt x m16
    f32x4 svv[2];
#pragma unroll
    for (int rt = 0; rt < 2; ++rt) {
      f32x4 mxv, sv;
#pragma unroll
      for (int i = 0; i < 4; ++i)
        mxv[i] = fmaxf(fmaxf(sacc[rt][0][i], sacc[rt][1][i]),
                       fmaxf(sacc[rt][2][i], sacc[rt][3][i]));
#pragma unroll
      for (int msk = 1; msk < 16; msk <<= 1)
#pragma unroll
        for (int i = 0; i < 4; ++i) mxv[i] = fmaxf(mxv[i], __shfl_xor(mxv[i], msk));
#pragma unroll
      for (int i = 0; i < 4; ++i) sv[i] = 0.f;
#pragma unroll
      for (int nt = 0; nt < 4; ++nt)
#pragma unroll
        for (int i = 0; i < 4; ++i) {
          float e = exp2_fast(sacc[rt][nt][i] - mxv[i]);
          sacc[rt][nt][i] = e;
          sv[i] += e;
        }
      // P (unnormalized) -> LDS immediately; sum-reduce overlaps
#pragma unroll
      for (int nt = 0; nt < 4; ++nt)
#pragma unroll
        for (int i = 0; i < 4; ++i)
          Ps[(tr0 + rt * 16 + quad * 4 + i) * 68 + nt * 16 + m16] = f2bf(sacc[rt][nt][i]);
#pragma unroll
      for (int msk = 1; msk < 16; msk <<= 1)
#pragma unroll
        for (int i = 0; i < 4; ++i) sv[i] += __shfl_xor(sv[i], msk);
#pragma unroll
      for (int i = 0; i < 4; ++i) svv[rt][i] = 1.f / sv[i];
    }

    // x = (P @ vcT) * (1/l)
    f32x4 acc2[2][2];
#pragma unroll
    for (int rt = 0; rt < 2; ++rt)
#pragma unroll
      for (int nt2 = 0; nt2 < 2; ++nt2) acc2[rt][nt2] = (f32x4){0.f, 0.f, 0.f, 0.f};
#pragma unroll
    for (int kc2 = 0; kc2 < 2; ++kc2) {
      bf16x8 pf[2];
#pragma unroll
      for (int rt = 0; rt < 2; ++rt)
        pf[rt] = *(const bf16x8*)&Ps[(tr0 + rt * 16 + m16) * 68 + kc2 * 32 + quad * 8];
#pragma unroll
      for (int rt = 0; rt < 2; ++rt)
#pragma unroll
        for (int nt2 = 0; nt2 < 2; ++nt2)
          acc2[rt][nt2] = __builtin_amdgcn_mfma_f32_16x16x32_bf16(pf[rt], vtf[nt2][kc2], acc2[rt][nt2], 0, 0, 0);
    }

    // stage x into Ps cols 0..32 (same-wave in-order LDS ops), coalesced store
#pragma unroll
    for (int rt = 0; rt < 2; ++rt)
#pragma unroll
      for (int nt2 = 0; nt2 < 2; ++nt2)
#pragma unroll
        for (int i = 0; i < 4; ++i)
          Ps[(tr0 + rt * 16 + quad * 4 + i) * 68 + nt2 * 16 + m16] =
              f2bf(acc2[rt][nt2][i] * svv[rt][i]);
    {
      int rr = tr0 + (lane >> 1), sel = lane & 1;
      ushort8 xv0 = *(const ushort8*)&Ps[rr * 68 + sel * 16];
      ushort8 xv1 = *(const ushort8*)&Ps[rr * 68 + sel * 16 + 8];
      unsigned short* gp = xout + (size_t)(bm + rr) * 256 + h * 32 + sel * 16;
      *(ushort8*)gp = xv0;
      *(ushort8*)(gp + 8) = xv1;
    }
  }
}

extern "C" void kernel_launch(void* const* d_in, const int* in_sizes, int n_in,
                              void* d_out, int out_size, void* d_ws, size_t ws_size,
                              hipStream_t stream) {
  const float* voxel  = (const float*)d_in[0];
  const float* A      = (const float*)d_in[1];
  const float* w_qkv  = (const float*)d_in[2];
  const float* w_proj = (const float*)d_in[3];
  const float* b_proj = (const float*)d_in[4];
  const float* cb     = (const float*)d_in[5];
  float* out = (float*)d_out;
  (void)in_sizes; (void)n_in; (void)out_size; (void)ws_size;

  // ws layout (byte offsets / sizes):
  // qb      0         33554432   (x output of qattn -> proj input)
  // xb      33554432  33554432   (X bf16)
  // part    67108864  16777216
  // asump   83886080  65536
  // wqT     83951616  131072
  // wpT     84082688  131072
  // kcb     84213760  131072
  // vcbT    84344832  131072
  // cbbT    84475904  8192
  char* wsb = (char*)d_ws;
  unsigned short* qb       = (unsigned short*)wsb;
  unsigned short* xb       = (unsigned short*)(wsb + 33554432);
  float* part              = (float*)(wsb + 67108864);
  float* asump             = (float*)(wsb + 83886080);
  unsigned short* wqT      = (unsigned short*)(wsb + 83951616);
  unsigned short* wpT      = (unsigned short*)(wsb + 84082688);
  unsigned short* kcb      = (unsigned short*)(wsb + 84213760);
  unsigned short* vcbT     = (unsigned short*)(wsb + 84344832);
  unsigned short* cbbT     = (unsigned short*)(wsb + 84475904);
  // Ab (bf16 A, 8 MB) parked in d_out: dead before the final GEMM writes out
  unsigned short* Ab = (unsigned short*)d_out;

  // fused conversions (voxel/A bf16 + weight transposes)
  convall<<<2561, 256, 0, stream>>>(voxel, A, w_qkv, w_proj, cb,
                                    xb, Ab, wqT, wpT, cbbT);

  // pooledX partials = A^T @ X per 256-token chunk (+ chunk A-sums)
  pool_mfma<<<dim3(64, 2, BATCH), 256, 0, stream>>>(Ab, xb, part, asump);
  // fused reduce + denom + fp32 K/V mini-GEMM
  pool2kv<<<256, 256, 0, stream>>>(part, asump, w_qkv, kcb, vcbT);

  // fused Q-GEMM + attention: 128 tokens x 4 heads per block; x -> qb
  qattn<<<dim3(2, 512), 256, 0, stream>>>(xb, wqT, Ab, kcb, vcbT, cbbT, qb);

  // out = x @ w_proj + b_proj (x bf16 in qb, lda 256)
  gemm_proj<<<dim3(2, 512), 256, 0, stream>>>(qb, wpT, b_proj, out,
                                              256, 256, 256);
}